// Round 8
// baseline (195.776 us; speedup 1.0000x reference)
//
#include <hip/hip_runtime.h>

// Problem constants (fixed by the reference)
constexpr int Bn = 4, Nn = 5000, Kd = 20, Hh = 128;
constexpr int Ee = Nn * Kd;  // 100000

typedef __attribute__((ext_vector_type(8))) short bf16x8;
typedef __attribute__((ext_vector_type(4))) float f32x4;

__device__ __forceinline__ short f2bf(float f) {
  unsigned int u = __builtin_bit_cast(unsigned int, f);
  u += 0x7fffu + ((u >> 16) & 1u);  // RNE (finite inputs only)
  return (short)(u >> 16);
}

__device__ __forceinline__ bf16x8 cvt8(const float* __restrict__ p) {
  f32x4 lo = *reinterpret_cast<const f32x4*>(p);
  f32x4 hi = *reinterpret_cast<const f32x4*>(p + 4);
  bf16x8 r;
  #pragma unroll
  for (int i = 0; i < 4; ++i) { r[i] = f2bf(lo[i]); r[4 + i] = f2bf(hi[i]); }
  return r;
}

// Nontemporal variant: read-once streaming data, don't retain in cache.
__device__ __forceinline__ bf16x8 cvt8_nt(const float* __restrict__ p) {
  f32x4 lo = __builtin_nontemporal_load(reinterpret_cast<const f32x4*>(p));
  f32x4 hi = __builtin_nontemporal_load(reinterpret_cast<const f32x4*>(p) + 1);
  bf16x8 r;
  #pragma unroll
  for (int i = 0; i < 4; ++i) { r[i] = f2bf(lo[i]); r[4 + i] = f2bf(hi[i]); }
  return r;
}

// ---------------------------------------------------------------------------
// Kernel 0: bf16 weights, fused bias (biasA = U_b + iU_b, folded into VxF),
// placeholder correction row (corr = W_ph - iU_b), zero gather row.
// ---------------------------------------------------------------------------
__global__ void __launch_bounds__(256) prep_kernel(
    const float* __restrict__ U_w, const float* __restrict__ iU_w,
    const float* __restrict__ Vf_w, const float* __restrict__ Vt_w,
    const float* __restrict__ U_b, const float* __restrict__ iU_b,
    const float* __restrict__ W_ph,
    short* __restrict__ Ubf, short* __restrict__ iUbf,
    short* __restrict__ Vfbf, short* __restrict__ Vtbf,
    float* __restrict__ biasA, float* __restrict__ corr,
    float* __restrict__ zrow) {
  int t = blockIdx.x * blockDim.x + threadIdx.x;
  if (t < Hh * Hh) {
    Ubf[t]  = f2bf(U_w[t]);
    iUbf[t] = f2bf(iU_w[t]);
    Vfbf[t] = f2bf(Vf_w[t]);
    Vtbf[t] = f2bf(Vt_w[t]);
  }
  if (t < Hh) {
    biasA[t] = U_b[t] + iU_b[t];
    corr[t]  = W_ph[t] - iU_b[t];
    zrow[t]  = 0.0f;
  }
}

// ---------------------------------------------------------------------------
// Kernel 1: VxF = x @ Vf_w^T + (Vf_b + U_b + iU_b), VxT = x @ Vt_w^T + Vt_b.
// ---------------------------------------------------------------------------
__global__ void __launch_bounds__(256) vxproj_kernel(
    const float* __restrict__ x,
    const short* __restrict__ Vfbf, const short* __restrict__ Vtbf,
    const float* __restrict__ Vf_b, const float* __restrict__ Vt_b,
    const float* __restrict__ biasA,
    float* __restrict__ VxF, float* __restrict__ VxT) {
  int wave = (int)((blockIdx.x * blockDim.x + threadIdx.x) >> 6);
  constexpr int NW = (Bn * Nn) / 16;  // 1250
  if (wave >= NW) return;
  int lane = threadIdx.x & 63;
  int r = lane & 15, kg = lane >> 4;
  int row0 = wave * 16;
  const float* xrow = x + (size_t)(row0 + r) * Hh;

  f32x4 accF[8], accT[8];
  #pragma unroll
  for (int ht = 0; ht < 8; ++ht) {
    accF[ht] = (f32x4)(0.0f);
    accT[ht] = (f32x4)(0.0f);
  }

  #pragma unroll
  for (int kk = 0; kk < 4; ++kk) {
    int k0 = kk * 32 + kg * 8;
    bf16x8 a = cvt8(xrow + k0);
    #pragma unroll
    for (int ht = 0; ht < 8; ++ht) {
      bf16x8 bF = *reinterpret_cast<const bf16x8*>(Vfbf + (ht * 16 + r) * Hh + k0);
      bf16x8 bT = *reinterpret_cast<const bf16x8*>(Vtbf + (ht * 16 + r) * Hh + k0);
      accF[ht] = __builtin_amdgcn_mfma_f32_16x16x32_bf16(a, bF, accF[ht], 0, 0, 0);
      accT[ht] = __builtin_amdgcn_mfma_f32_16x16x32_bf16(a, bT, accT[ht], 0, 0, 0);
    }
  }

  #pragma unroll
  for (int ht = 0; ht < 8; ++ht) {
    int h = ht * 16 + r;
    float bf = Vf_b[h] + biasA[h];
    float bt = Vt_b[h];
    #pragma unroll
    for (int i = 0; i < 4; ++i) {
      size_t row = (size_t)(row0 + kg * 4 + i);
      VxF[row * Hh + h] = accF[ht][i] + bf;
      VxT[row * Hh + h] = accT[ht][i] + bt;
    }
  }
}

// ---------------------------------------------------------------------------
// Kernel 2: main fused per-edge kernel (v7 = round-5 base + C-init hoist +
// NT hint on the read-once coalesced e-stream).
//   - 32 edges/wave, 8 waves/block, launch_bounds(512,3): no spill (verified
//     config), ~12 waves/CU.
//   - gathered a2 fragments staged up-front; vt/vf gathers folded into the
//     MFMA C-operand BEFORE the K-loop (no serial epilogue loads).
//   - a1 (coalesced, read-once) loads carry nontemporal hint so the 205 MB
//     stream does not evict the L3-resident gather working set.
//   - epilogue: plain f32x4 stores only.
// ---------------------------------------------------------------------------
__global__ void __launch_bounds__(512, 3) edge_kernel(
    const float* __restrict__ e,
    const int* __restrict__ edge_index,
    const int* __restrict__ inv_edge_index,
    const short* __restrict__ Ubf, const short* __restrict__ iUbf,
    const float* __restrict__ corr, const float* __restrict__ zrow,
    const float* __restrict__ VxF, const float* __restrict__ VxT,
    float* __restrict__ out) {
  __shared__ short wlds[2 * Hh * Hh];  // 64 KiB, XOR-swizzled 16B chunks
  #pragma unroll
  for (int it = 0; it < 8; ++it) {
    int idx = it * 512 + (int)threadIdx.x;   // 0..4095
    int m = idx >> 11;
    int rr = idx & 2047;
    int h = rr >> 4, kb = rr & 15;
    const short* src = (m ? iUbf : Ubf) + h * Hh + kb * 8;
    bf16x8 v = *reinterpret_cast<const bf16x8*>(src);
    int dst = m * (Hh * Hh) + h * Hh + ((kb ^ (h & 15)) << 3);
    *reinterpret_cast<bf16x8*>(wlds + dst) = v;
  }
  __syncthreads();

  int wv = (int)((blockIdx.x * blockDim.x + threadIdx.x) >> 6);
  if (wv < Bn * (Ee / 32)) {
    int lane = threadIdx.x & 63;
    int c = lane & 15, kg = lane >> 4;
    constexpr int WPB = Ee / 32;  // 3125
    int b = wv / WPB;
    int j0 = (wv % WPB) * 32;
    const size_t ebase = (size_t)b * Ee;
    const float* ebat = e + ebase * Hh;

    int jc[2] = {j0 + c, j0 + 16 + c};
    int i2[2], ei[2];
    bool ph[2];
    const float* a2r[2];
    #pragma unroll
    for (int et = 0; et < 2; ++et) {
      i2[et] = inv_edge_index[ebase + jc[et]];
      ei[et] = edge_index[ebase + jc[et]];
      ph[et] = (i2[et] == Ee);
      a2r[et] = ph[et] ? zrow : (ebat + (size_t)i2[et] * Hh);
    }

    // Stage ALL gathered fragments first (longest-latency loads issue early).
    bf16x8 a2f[2][4];
    #pragma unroll
    for (int et = 0; et < 2; ++et)
      #pragma unroll
      for (int kk = 0; kk < 4; ++kk)
        a2f[et][kk] = cvt8(a2r[et] + kk * 32 + kg * 8);

    // C-init: acc = VxT[ei] + VxF[j/K] (+corr for rare placeholder edges).
    f32x4 acc[2][8];
    #pragma unroll
    for (int et = 0; et < 2; ++et) {
      const float* vt = VxT + ((size_t)b * Nn + ei[et]) * Hh;
      const float* vf = VxF + ((size_t)b * Nn + jc[et] / Kd) * Hh;
      #pragma unroll
      for (int ht = 0; ht < 8; ++ht) {
        int h0 = ht * 16 + kg * 4;
        f32x4 vt4 = *reinterpret_cast<const f32x4*>(vt + h0);
        f32x4 vf4 = *reinterpret_cast<const f32x4*>(vf + h0);
        acc[et][ht] = vt4 + vf4;
      }
      if (ph[et]) {  // p ~ 1e-5: exec-masked, usually branched over
        #pragma unroll
        for (int ht = 0; ht < 8; ++ht) {
          int h0 = ht * 16 + kg * 4;
          acc[et][ht] += *reinterpret_cast<const f32x4*>(corr + h0);
        }
      }
    }

    // K-loop: NT-hinted coalesced a1 loads + LDS weight reads + MFMA.
    #pragma unroll
    for (int kk = 0; kk < 4; ++kk) {
      int k0 = kk * 32 + kg * 8;
      bf16x8 a1[2];
      #pragma unroll
      for (int et = 0; et < 2; ++et)
        a1[et] = cvt8_nt(ebat + (size_t)jc[et] * Hh + k0);
      #pragma unroll
      for (int ht = 0; ht < 8; ++ht) {
        int h = ht * 16 + c;
        int off = h * Hh + ((((kk << 2) + kg) ^ (h & 15)) << 3);
        bf16x8 wu = *reinterpret_cast<const bf16x8*>(wlds + off);
        bf16x8 wi = *reinterpret_cast<const bf16x8*>(wlds + Hh * Hh + off);
        #pragma unroll
        for (int et = 0; et < 2; ++et) {
          acc[et][ht] = __builtin_amdgcn_mfma_f32_16x16x32_bf16(wu, a1[et], acc[et][ht], 0, 0, 0);
          acc[et][ht] = __builtin_amdgcn_mfma_f32_16x16x32_bf16(wi, a2f[et][kk], acc[et][ht], 0, 0, 0);
        }
      }
    }

    // Epilogue: pure stores.
    #pragma unroll
    for (int et = 0; et < 2; ++et) {
      float* orow = out + (ebase + (size_t)jc[et]) * Hh;
      #pragma unroll
      for (int ht = 0; ht < 8; ++ht) {
        int h0 = ht * 16 + kg * 4;
        *reinterpret_cast<f32x4*>(orow + h0) = acc[et][ht];
      }
    }
  }
}

extern "C" void kernel_launch(void* const* d_in, const int* in_sizes, int n_in,
                              void* d_out, int out_size, void* d_ws, size_t ws_size,
                              hipStream_t stream) {
  const float* x   = (const float*)d_in[0];
  const float* e   = (const float*)d_in[1];
  const int* edge_index = (const int*)d_in[2];
  const int* inv_edge_index = (const int*)d_in[3];
  const float* U_w  = (const float*)d_in[4];
  const float* U_b  = (const float*)d_in[5];
  const float* Vf_w = (const float*)d_in[6];
  const float* Vf_b = (const float*)d_in[7];
  const float* Vt_w = (const float*)d_in[8];
  const float* Vt_b = (const float*)d_in[9];
  const float* iU_w = (const float*)d_in[10];
  const float* iU_b = (const float*)d_in[11];
  const float* W_ph = (const float*)d_in[12];
  float* out = (float*)d_out;

  // Workspace layout
  float* VxF   = (float*)d_ws;                         // B*N*H floats
  float* VxT   = VxF + (size_t)Bn * Nn * Hh;           // B*N*H floats
  float* biasA = VxT + (size_t)Bn * Nn * Hh;           // 128
  float* corr  = biasA + Hh;                           // 128
  float* zrow  = corr + Hh;                            // 128 (zero row)
  short* Ubf   = (short*)(zrow + Hh);                  // 16384 shorts each
  short* iUbf  = Ubf + Hh * Hh;
  short* Vfbf  = iUbf + Hh * Hh;
  short* Vtbf  = Vfbf + Hh * Hh;

  prep_kernel<<<dim3(64), dim3(256), 0, stream>>>(
      U_w, iU_w, Vf_w, Vt_w, U_b, iU_b, W_ph, Ubf, iUbf, Vfbf, Vtbf,
      biasA, corr, zrow);

  vxproj_kernel<<<dim3(313), dim3(256), 0, stream>>>(
      x, Vfbf, Vtbf, Vf_b, Vt_b, biasA, VxF, VxT);

  int nwaves = Bn * (Ee / 32);                 // 12500
  int nblocks = (nwaves + 7) / 8;              // 1563 blocks of 512 threads
  edge_kernel<<<dim3(nblocks), dim3(512), 0, stream>>>(
      e, edge_index, inv_edge_index, Ubf, iUbf, corr, zrow, VxF, VxT, out);
}

// Round 9
// 174.679 us; speedup vs baseline: 1.1208x; 1.1208x over previous
//
#include <hip/hip_runtime.h>

// Problem constants (fixed by the reference)
constexpr int Bn = 4, Nn = 5000, Kd = 20, Hh = 128;
constexpr int Ee = Nn * Kd;  // 100000

typedef __attribute__((ext_vector_type(8))) short bf16x8;
typedef __attribute__((ext_vector_type(4))) float f32x4;

__device__ __forceinline__ short f2bf(float f) {
  unsigned int u = __builtin_bit_cast(unsigned int, f);
  u += 0x7fffu + ((u >> 16) & 1u);  // RNE (finite inputs only)
  return (short)(u >> 16);
}

__device__ __forceinline__ bf16x8 cvt8(const float* __restrict__ p) {
  f32x4 lo = *reinterpret_cast<const f32x4*>(p);
  f32x4 hi = *reinterpret_cast<const f32x4*>(p + 4);
  bf16x8 r;
  #pragma unroll
  for (int i = 0; i < 4; ++i) { r[i] = f2bf(lo[i]); r[4 + i] = f2bf(hi[i]); }
  return r;
}

// ---------------------------------------------------------------------------
// Kernel 0: bf16 weights, fused bias (biasA = U_b + iU_b, folded into VxF),
// placeholder correction row (corr = W_ph - iU_b), zero gather row.
// ---------------------------------------------------------------------------
__global__ void __launch_bounds__(256) prep_kernel(
    const float* __restrict__ U_w, const float* __restrict__ iU_w,
    const float* __restrict__ Vf_w, const float* __restrict__ Vt_w,
    const float* __restrict__ U_b, const float* __restrict__ iU_b,
    const float* __restrict__ W_ph,
    short* __restrict__ Ubf, short* __restrict__ iUbf,
    short* __restrict__ Vfbf, short* __restrict__ Vtbf,
    float* __restrict__ biasA, float* __restrict__ corr,
    float* __restrict__ zrow) {
  int t = blockIdx.x * blockDim.x + threadIdx.x;
  if (t < Hh * Hh) {
    Ubf[t]  = f2bf(U_w[t]);
    iUbf[t] = f2bf(iU_w[t]);
    Vfbf[t] = f2bf(Vf_w[t]);
    Vtbf[t] = f2bf(Vt_w[t]);
  }
  if (t < Hh) {
    biasA[t] = U_b[t] + iU_b[t];
    corr[t]  = W_ph[t] - iU_b[t];
    zrow[t]  = 0.0f;
  }
}

// ---------------------------------------------------------------------------
// Kernel 1: VxF = x @ Vf_w^T + (Vf_b + U_b + iU_b), VxT = x @ Vt_w^T + Vt_b.
// ---------------------------------------------------------------------------
__global__ void __launch_bounds__(256) vxproj_kernel(
    const float* __restrict__ x,
    const short* __restrict__ Vfbf, const short* __restrict__ Vtbf,
    const float* __restrict__ Vf_b, const float* __restrict__ Vt_b,
    const float* __restrict__ biasA,
    float* __restrict__ VxF, float* __restrict__ VxT) {
  int wave = (int)((blockIdx.x * blockDim.x + threadIdx.x) >> 6);
  constexpr int NW = (Bn * Nn) / 16;  // 1250
  if (wave >= NW) return;
  int lane = threadIdx.x & 63;
  int r = lane & 15, kg = lane >> 4;
  int row0 = wave * 16;
  const float* xrow = x + (size_t)(row0 + r) * Hh;

  f32x4 accF[8], accT[8];
  #pragma unroll
  for (int ht = 0; ht < 8; ++ht) {
    accF[ht] = (f32x4)(0.0f);
    accT[ht] = (f32x4)(0.0f);
  }

  #pragma unroll
  for (int kk = 0; kk < 4; ++kk) {
    int k0 = kk * 32 + kg * 8;
    bf16x8 a = cvt8(xrow + k0);
    #pragma unroll
    for (int ht = 0; ht < 8; ++ht) {
      bf16x8 bF = *reinterpret_cast<const bf16x8*>(Vfbf + (ht * 16 + r) * Hh + k0);
      bf16x8 bT = *reinterpret_cast<const bf16x8*>(Vtbf + (ht * 16 + r) * Hh + k0);
      accF[ht] = __builtin_amdgcn_mfma_f32_16x16x32_bf16(a, bF, accF[ht], 0, 0, 0);
      accT[ht] = __builtin_amdgcn_mfma_f32_16x16x32_bf16(a, bT, accT[ht], 0, 0, 0);
    }
  }

  #pragma unroll
  for (int ht = 0; ht < 8; ++ht) {
    int h = ht * 16 + r;
    float bf = Vf_b[h] + biasA[h];
    float bt = Vt_b[h];
    #pragma unroll
    for (int i = 0; i < 4; ++i) {
      size_t row = (size_t)(row0 + kg * 4 + i);
      VxF[row * Hh + h] = accF[ht][i] + bf;
      VxT[row * Hh + h] = accT[ht][i] + bt;
    }
  }
}

// ---------------------------------------------------------------------------
// Kernel 2: main fused per-edge kernel (v9 = r6 structure, de-spilled,
// XCD-swizzled, no NT hints).
//   - 16 edges/wave (2x the independent gather streams per CU vs 32-edge),
//     8 waves/block, launch_bounds(512,3): ~170-reg budget -> no spill.
//   - ALL fragments (a1 coalesced + a2 gathered) front-loaded; VxT/VxF
//     gathers folded into the MFMA C-operand before the K-loop.
//   - bijective XCD swizzle: blocks resident on XCD k process a contiguous
//     edge range -> per-XCD L2 keeps one 2.5 MB VxT slice resident.
//   - epilogue: pure plain f32x4 stores.
// ---------------------------------------------------------------------------
constexpr int NBLK = (Bn * Ee) / (16 * 8);  // 3125 blocks of 8 waves

__global__ void __launch_bounds__(512, 3) edge_kernel(
    const float* __restrict__ e,
    const int* __restrict__ edge_index,
    const int* __restrict__ inv_edge_index,
    const short* __restrict__ Ubf, const short* __restrict__ iUbf,
    const float* __restrict__ corr, const float* __restrict__ zrow,
    const float* __restrict__ VxF, const float* __restrict__ VxT,
    float* __restrict__ out) {
  __shared__ short wlds[2 * Hh * Hh];  // 64 KiB, XOR-swizzled 16B chunks
  #pragma unroll
  for (int it = 0; it < 8; ++it) {
    int idx = it * 512 + (int)threadIdx.x;   // 0..4095
    int m = idx >> 11;
    int rr = idx & 2047;
    int h = rr >> 4, kb = rr & 15;
    const short* src = (m ? iUbf : Ubf) + h * Hh + kb * 8;
    bf16x8 v = *reinterpret_cast<const bf16x8*>(src);
    int dst = m * (Hh * Hh) + h * Hh + ((kb ^ (h & 15)) << 3);
    *reinterpret_cast<bf16x8*>(wlds + dst) = v;
  }
  __syncthreads();

  // Bijective XCD-aware swizzle (m204): XCD k = blockIdx%8 gets contiguous
  // work chunk k. NBLK = 3125 = 8*390 + 5.
  {
    constexpr int q = NBLK / 8, r8 = NBLK % 8;  // 390, 5
    int bid = (int)blockIdx.x;
    int xcd = bid & 7, bi = bid >> 3;
    int sbid = (xcd < r8 ? xcd * (q + 1) : r8 * (q + 1) + (xcd - r8) * q) + bi;

    int wv = sbid * 8 + ((int)threadIdx.x >> 6);  // 0..24999
    int lane = threadIdx.x & 63;
    int c = lane & 15, kg = lane >> 4;
    constexpr int WPB = Ee / 16;  // 6250 waves per batch
    int b = wv / WPB;
    int j = (wv % WPB) * 16 + c;         // this lane's edge (B column c)
    const size_t ebase = (size_t)b * Ee;
    const float* ebat = e + ebase * Hh;

    int i2 = inv_edge_index[ebase + j];
    int ei = edge_index[ebase + j];
    bool ph = (i2 == Ee);
    const float* a1r = ebat + (size_t)j * Hh;
    const float* a2r = ph ? zrow : (ebat + (size_t)i2 * Hh);

    // Front-load ALL fragments (coalesced stream + gathered rows).
    bf16x8 a1f[4], a2f[4];
    #pragma unroll
    for (int kk = 0; kk < 4; ++kk) {
      int k0 = kk * 32 + kg * 8;
      a1f[kk] = cvt8(a1r + k0);
      a2f[kk] = cvt8(a2r + k0);
    }

    // C-init: acc = VxT[ei] + VxF[j/K] (+corr for rare placeholder edges).
    const float* vt = VxT + ((size_t)b * Nn + ei) * Hh;
    const float* vf = VxF + ((size_t)b * Nn + j / Kd) * Hh;
    f32x4 acc[8];
    #pragma unroll
    for (int ht = 0; ht < 8; ++ht) {
      int h0 = ht * 16 + kg * 4;
      f32x4 vt4 = *reinterpret_cast<const f32x4*>(vt + h0);
      f32x4 vf4 = *reinterpret_cast<const f32x4*>(vf + h0);
      acc[ht] = vt4 + vf4;
    }
    if (ph) {  // p ~ 1e-5: exec-masked, usually branched over
      #pragma unroll
      for (int ht = 0; ht < 8; ++ht) {
        int h0 = ht * 16 + kg * 4;
        acc[ht] += *reinterpret_cast<const f32x4*>(corr + h0);
      }
    }

    // K-loop: pure LDS weight reads + MFMA.
    #pragma unroll
    for (int kk = 0; kk < 4; ++kk) {
      #pragma unroll
      for (int ht = 0; ht < 8; ++ht) {
        int h = ht * 16 + c;
        int off = h * Hh + ((((kk << 2) + kg) ^ (h & 15)) << 3);
        bf16x8 wu = *reinterpret_cast<const bf16x8*>(wlds + off);
        bf16x8 wi = *reinterpret_cast<const bf16x8*>(wlds + Hh * Hh + off);
        acc[ht] = __builtin_amdgcn_mfma_f32_16x16x32_bf16(wu, a1f[kk], acc[ht], 0, 0, 0);
        acc[ht] = __builtin_amdgcn_mfma_f32_16x16x32_bf16(wi, a2f[kk], acc[ht], 0, 0, 0);
      }
    }

    // Epilogue: pure stores.
    float* orow = out + (ebase + (size_t)j) * Hh;
    #pragma unroll
    for (int ht = 0; ht < 8; ++ht) {
      int h0 = ht * 16 + kg * 4;
      *reinterpret_cast<f32x4*>(orow + h0) = acc[ht];
    }
  }
}

extern "C" void kernel_launch(void* const* d_in, const int* in_sizes, int n_in,
                              void* d_out, int out_size, void* d_ws, size_t ws_size,
                              hipStream_t stream) {
  const float* x   = (const float*)d_in[0];
  const float* e   = (const float*)d_in[1];
  const int* edge_index = (const int*)d_in[2];
  const int* inv_edge_index = (const int*)d_in[3];
  const float* U_w  = (const float*)d_in[4];
  const float* U_b  = (const float*)d_in[5];
  const float* Vf_w = (const float*)d_in[6];
  const float* Vf_b = (const float*)d_in[7];
  const float* Vt_w = (const float*)d_in[8];
  const float* Vt_b = (const float*)d_in[9];
  const float* iU_w = (const float*)d_in[10];
  const float* iU_b = (const float*)d_in[11];
  const float* W_ph = (const float*)d_in[12];
  float* out = (float*)d_out;

  // Workspace layout
  float* VxF   = (float*)d_ws;                         // B*N*H floats
  float* VxT   = VxF + (size_t)Bn * Nn * Hh;           // B*N*H floats
  float* biasA = VxT + (size_t)Bn * Nn * Hh;           // 128
  float* corr  = biasA + Hh;                           // 128
  float* zrow  = corr + Hh;                            // 128 (zero row)
  short* Ubf   = (short*)(zrow + Hh);                  // 16384 shorts each
  short* iUbf  = Ubf + Hh * Hh;
  short* Vfbf  = iUbf + Hh * Hh;
  short* Vtbf  = Vfbf + Hh * Hh;

  prep_kernel<<<dim3(64), dim3(256), 0, stream>>>(
      U_w, iU_w, Vf_w, Vt_w, U_b, iU_b, W_ph, Ubf, iUbf, Vfbf, Vtbf,
      biasA, corr, zrow);

  vxproj_kernel<<<dim3(313), dim3(256), 0, stream>>>(
      x, Vfbf, Vtbf, Vf_b, Vt_b, biasA, VxF, VxT);

  edge_kernel<<<dim3(NBLK), dim3(512), 0, stream>>>(
      e, edge_index, inv_edge_index, Ubf, iUbf, corr, zrow, VxF, VxT, out);
}

// Round 10
// 158.867 us; speedup vs baseline: 1.2323x; 1.0995x over previous
//
#include <hip/hip_runtime.h>

// Problem constants (fixed by the reference)
constexpr int Bn = 4, Nn = 5000, Kd = 20, Hh = 128;
constexpr int Ee = Nn * Kd;  // 100000

typedef __attribute__((ext_vector_type(8))) short bf16x8;
typedef __attribute__((ext_vector_type(4))) float f32x4;

__device__ __forceinline__ short f2bf(float f) {
  unsigned int u = __builtin_bit_cast(unsigned int, f);
  u += 0x7fffu + ((u >> 16) & 1u);  // RNE (finite inputs only)
  return (short)(u >> 16);
}

__device__ __forceinline__ bf16x8 cvt8(const float* __restrict__ p) {
  f32x4 lo = *reinterpret_cast<const f32x4*>(p);
  f32x4 hi = *reinterpret_cast<const f32x4*>(p + 4);
  bf16x8 r;
  #pragma unroll
  for (int i = 0; i < 4; ++i) { r[i] = f2bf(lo[i]); r[4 + i] = f2bf(hi[i]); }
  return r;
}

// ---------------------------------------------------------------------------
// Kernel 0: bf16 weights, fused bias (biasA = U_b + iU_b, folded into VxF),
// placeholder correction row (corr = W_ph - iU_b), zero gather row.
// ---------------------------------------------------------------------------
__global__ void __launch_bounds__(256) prep_kernel(
    const float* __restrict__ U_w, const float* __restrict__ iU_w,
    const float* __restrict__ Vf_w, const float* __restrict__ Vt_w,
    const float* __restrict__ U_b, const float* __restrict__ iU_b,
    const float* __restrict__ W_ph,
    short* __restrict__ Ubf, short* __restrict__ iUbf,
    short* __restrict__ Vfbf, short* __restrict__ Vtbf,
    float* __restrict__ biasA, float* __restrict__ corr,
    float* __restrict__ zrow) {
  int t = blockIdx.x * blockDim.x + threadIdx.x;
  if (t < Hh * Hh) {
    Ubf[t]  = f2bf(U_w[t]);
    iUbf[t] = f2bf(iU_w[t]);
    Vfbf[t] = f2bf(Vf_w[t]);
    Vtbf[t] = f2bf(Vt_w[t]);
  }
  if (t < Hh) {
    biasA[t] = U_b[t] + iU_b[t];
    corr[t]  = W_ph[t] - iU_b[t];
    zrow[t]  = 0.0f;
  }
}

// ---------------------------------------------------------------------------
// Kernel 1: VxF = x @ Vf_w^T + (Vf_b + U_b + iU_b), VxT = x @ Vt_w^T + Vt_b.
// ---------------------------------------------------------------------------
__global__ void __launch_bounds__(256) vxproj_kernel(
    const float* __restrict__ x,
    const short* __restrict__ Vfbf, const short* __restrict__ Vtbf,
    const float* __restrict__ Vf_b, const float* __restrict__ Vt_b,
    const float* __restrict__ biasA,
    float* __restrict__ VxF, float* __restrict__ VxT) {
  int wave = (int)((blockIdx.x * blockDim.x + threadIdx.x) >> 6);
  constexpr int NW = (Bn * Nn) / 16;  // 1250
  if (wave >= NW) return;
  int lane = threadIdx.x & 63;
  int r = lane & 15, kg = lane >> 4;
  int row0 = wave * 16;
  const float* xrow = x + (size_t)(row0 + r) * Hh;

  f32x4 accF[8], accT[8];
  #pragma unroll
  for (int ht = 0; ht < 8; ++ht) {
    accF[ht] = (f32x4)(0.0f);
    accT[ht] = (f32x4)(0.0f);
  }

  #pragma unroll
  for (int kk = 0; kk < 4; ++kk) {
    int k0 = kk * 32 + kg * 8;
    bf16x8 a = cvt8(xrow + k0);
    #pragma unroll
    for (int ht = 0; ht < 8; ++ht) {
      bf16x8 bF = *reinterpret_cast<const bf16x8*>(Vfbf + (ht * 16 + r) * Hh + k0);
      bf16x8 bT = *reinterpret_cast<const bf16x8*>(Vtbf + (ht * 16 + r) * Hh + k0);
      accF[ht] = __builtin_amdgcn_mfma_f32_16x16x32_bf16(a, bF, accF[ht], 0, 0, 0);
      accT[ht] = __builtin_amdgcn_mfma_f32_16x16x32_bf16(a, bT, accT[ht], 0, 0, 0);
    }
  }

  #pragma unroll
  for (int ht = 0; ht < 8; ++ht) {
    int h = ht * 16 + r;
    float bf = Vf_b[h] + biasA[h];
    float bt = Vt_b[h];
    #pragma unroll
    for (int i = 0; i < 4; ++i) {
      size_t row = (size_t)(row0 + kg * 4 + i);
      VxF[row * Hh + h] = accF[ht][i] + bf;
      VxT[row * Hh + h] = accT[ht][i] + bt;
    }
  }
}

// ---------------------------------------------------------------------------
// Kernel 2: main fused per-edge kernel (v10 = r9 + NT output stores ONLY).
//   - 16 edges/wave, 8 waves/block, launch_bounds(512,3): no spill (verified).
//   - ALL fragments (a1 coalesced + a2 gathered) front-loaded; VxT/VxF
//     gathers folded into the MFMA C-operand before the K-loop.
//   - bijective XCD swizzle (verified r9).
//   - NT stores: keep the 200 MB write stream out of L2 so the gather
//     working set (a2 rows + VxT) stays resident. Isolated A/B vs r9.
// ---------------------------------------------------------------------------
constexpr int NBLK = (Bn * Ee) / (16 * 8);  // 3125 blocks of 8 waves

__global__ void __launch_bounds__(512, 3) edge_kernel(
    const float* __restrict__ e,
    const int* __restrict__ edge_index,
    const int* __restrict__ inv_edge_index,
    const short* __restrict__ Ubf, const short* __restrict__ iUbf,
    const float* __restrict__ corr, const float* __restrict__ zrow,
    const float* __restrict__ VxF, const float* __restrict__ VxT,
    float* __restrict__ out) {
  __shared__ short wlds[2 * Hh * Hh];  // 64 KiB, XOR-swizzled 16B chunks
  #pragma unroll
  for (int it = 0; it < 8; ++it) {
    int idx = it * 512 + (int)threadIdx.x;   // 0..4095
    int m = idx >> 11;
    int rr = idx & 2047;
    int h = rr >> 4, kb = rr & 15;
    const short* src = (m ? iUbf : Ubf) + h * Hh + kb * 8;
    bf16x8 v = *reinterpret_cast<const bf16x8*>(src);
    int dst = m * (Hh * Hh) + h * Hh + ((kb ^ (h & 15)) << 3);
    *reinterpret_cast<bf16x8*>(wlds + dst) = v;
  }
  __syncthreads();

  // Bijective XCD-aware swizzle (m204): NBLK = 3125 = 8*390 + 5.
  {
    constexpr int q = NBLK / 8, r8 = NBLK % 8;  // 390, 5
    int bid = (int)blockIdx.x;
    int xcd = bid & 7, bi = bid >> 3;
    int sbid = (xcd < r8 ? xcd * (q + 1) : r8 * (q + 1) + (xcd - r8) * q) + bi;

    int wv = sbid * 8 + ((int)threadIdx.x >> 6);  // 0..24999
    int lane = threadIdx.x & 63;
    int c = lane & 15, kg = lane >> 4;
    constexpr int WPB = Ee / 16;  // 6250 waves per batch
    int b = wv / WPB;
    int j = (wv % WPB) * 16 + c;         // this lane's edge (B column c)
    const size_t ebase = (size_t)b * Ee;
    const float* ebat = e + ebase * Hh;

    int i2 = inv_edge_index[ebase + j];
    int ei = edge_index[ebase + j];
    bool ph = (i2 == Ee);
    const float* a1r = ebat + (size_t)j * Hh;
    const float* a2r = ph ? zrow : (ebat + (size_t)i2 * Hh);

    // Front-load ALL fragments (coalesced stream + gathered rows).
    bf16x8 a1f[4], a2f[4];
    #pragma unroll
    for (int kk = 0; kk < 4; ++kk) {
      int k0 = kk * 32 + kg * 8;
      a1f[kk] = cvt8(a1r + k0);
      a2f[kk] = cvt8(a2r + k0);
    }

    // C-init: acc = VxT[ei] + VxF[j/K] (+corr for rare placeholder edges).
    const float* vt = VxT + ((size_t)b * Nn + ei) * Hh;
    const float* vf = VxF + ((size_t)b * Nn + j / Kd) * Hh;
    f32x4 acc[8];
    #pragma unroll
    for (int ht = 0; ht < 8; ++ht) {
      int h0 = ht * 16 + kg * 4;
      f32x4 vt4 = *reinterpret_cast<const f32x4*>(vt + h0);
      f32x4 vf4 = *reinterpret_cast<const f32x4*>(vf + h0);
      acc[ht] = vt4 + vf4;
    }
    if (ph) {  // p ~ 1e-5: exec-masked, usually branched over
      #pragma unroll
      for (int ht = 0; ht < 8; ++ht) {
        int h0 = ht * 16 + kg * 4;
        acc[ht] += *reinterpret_cast<const f32x4*>(corr + h0);
      }
    }

    // K-loop: pure LDS weight reads + MFMA.
    #pragma unroll
    for (int kk = 0; kk < 4; ++kk) {
      #pragma unroll
      for (int ht = 0; ht < 8; ++ht) {
        int h = ht * 16 + c;
        int off = h * Hh + ((((kk << 2) + kg) ^ (h & 15)) << 3);
        bf16x8 wu = *reinterpret_cast<const bf16x8*>(wlds + off);
        bf16x8 wi = *reinterpret_cast<const bf16x8*>(wlds + Hh * Hh + off);
        acc[ht] = __builtin_amdgcn_mfma_f32_16x16x32_bf16(wu, a1f[kk], acc[ht], 0, 0, 0);
        acc[ht] = __builtin_amdgcn_mfma_f32_16x16x32_bf16(wi, a2f[kk], acc[ht], 0, 0, 0);
      }
    }

    // Epilogue: nontemporal stores (keep write stream out of L2).
    float* orow = out + (ebase + (size_t)j) * Hh;
    #pragma unroll
    for (int ht = 0; ht < 8; ++ht) {
      int h0 = ht * 16 + kg * 4;
      __builtin_nontemporal_store(acc[ht], reinterpret_cast<f32x4*>(orow + h0));
    }
  }
}

extern "C" void kernel_launch(void* const* d_in, const int* in_sizes, int n_in,
                              void* d_out, int out_size, void* d_ws, size_t ws_size,
                              hipStream_t stream) {
  const float* x   = (const float*)d_in[0];
  const float* e   = (const float*)d_in[1];
  const int* edge_index = (const int*)d_in[2];
  const int* inv_edge_index = (const int*)d_in[3];
  const float* U_w  = (const float*)d_in[4];
  const float* U_b  = (const float*)d_in[5];
  const float* Vf_w = (const float*)d_in[6];
  const float* Vf_b = (const float*)d_in[7];
  const float* Vt_w = (const float*)d_in[8];
  const float* Vt_b = (const float*)d_in[9];
  const float* iU_w = (const float*)d_in[10];
  const float* iU_b = (const float*)d_in[11];
  const float* W_ph = (const float*)d_in[12];
  float* out = (float*)d_out;

  // Workspace layout
  float* VxF   = (float*)d_ws;                         // B*N*H floats
  float* VxT   = VxF + (size_t)Bn * Nn * Hh;           // B*N*H floats
  float* biasA = VxT + (size_t)Bn * Nn * Hh;           // 128
  float* corr  = biasA + Hh;                           // 128
  float* zrow  = corr + Hh;                            // 128 (zero row)
  short* Ubf   = (short*)(zrow + Hh);                  // 16384 shorts each
  short* iUbf  = Ubf + Hh * Hh;
  short* Vfbf  = iUbf + Hh * Hh;
  short* Vtbf  = Vfbf + Hh * Hh;

  prep_kernel<<<dim3(64), dim3(256), 0, stream>>>(
      U_w, iU_w, Vf_w, Vt_w, U_b, iU_b, W_ph, Ubf, iUbf, Vfbf, Vtbf,
      biasA, corr, zrow);

  vxproj_kernel<<<dim3(313), dim3(256), 0, stream>>>(
      x, Vfbf, Vtbf, Vf_b, Vt_b, biasA, VxF, VxT);

  edge_kernel<<<dim3(NBLK), dim3(512), 0, stream>>>(
      e, edge_index, inv_edge_index, Ubf, iUbf, corr, zrow, VxF, VxT, out);
}